// Round 1
// baseline (1695.664 us; speedup 1.0000x reference)
//
#include <hip/hip_runtime.h>
#include <math.h>

constexpr int N_NODES = 4096;
constexpr int E_EDGES = 131072;
constexpr int IND     = 1024;
constexpr int HID     = 512;
constexpr int OUTD    = 128;
constexpr int PEH     = 64;
constexpr int KHOP    = 10;
constexpr int NPE     = N_NODES * PEH;    // 262144
constexpr int NM      = N_NODES * OUTD;   // 524288

__constant__ float d_coeff[11] = {
    1.f/1024.f, 10.f/1024.f, 45.f/1024.f, 120.f/1024.f, 210.f/1024.f,
    252.f/1024.f, 210.f/1024.f, 120.f/1024.f, 45.f/1024.f, 10.f/1024.f, 1.f/1024.f};

__device__ __forceinline__ void rank1(float (&s)[4], float a, const float4 b) {
    s[0] = fmaf(a, b.x, s[0]);
    s[1] = fmaf(a, b.y, s[1]);
    s[2] = fmaf(a, b.z, s[2]);
    s[3] = fmaf(a, b.w, s[3]);
}

// ---------------- graph prep ----------------
__global__ void k_degrees(const int* __restrict__ src, const int* __restrict__ dst,
                          int* outdeg, int* indeg) {
    int e = blockIdx.x * blockDim.x + threadIdx.x;
    if (e < E_EDGES) {
        atomicAdd(&outdeg[src[e]], 1);
        atomicAdd(&indeg[dst[e]], 1);
    }
}

__global__ void k_invs(const int* __restrict__ outdeg, const int* __restrict__ indeg,
                       float* dinv, float* d2) {
    int i = blockIdx.x * blockDim.x + threadIdx.x;
    if (i < N_NODES) {
        int od = outdeg[i];
        dinv[i] = od > 0 ? 1.0f / sqrtf((float)od) : 0.0f;
        d2[i]   = 1.0f / sqrtf((float)indeg[i] + 1.0f);
    }
}

// exclusive prefix sum of 4096 counts, single wave
__global__ void k_scan(const int* __restrict__ cnt, int* __restrict__ rp) {
    int lane = threadIdx.x;  // 0..63
    int base = lane * 64;
    int sum = 0;
    for (int j = 0; j < 64; ++j) sum += cnt[base + j];
    int incl = sum;
    for (int off = 1; off < 64; off <<= 1) {
        int nv = __shfl_up(incl, off);
        if (lane >= off) incl += nv;
    }
    int run = incl - sum;  // exclusive prefix of this lane's chunk
    for (int j = 0; j < 64; ++j) { rp[base + j] = run; run += cnt[base + j]; }
    if (lane == 63) rp[N_NODES] = run;
}

__global__ void k_scatter(const int* __restrict__ src, const int* __restrict__ dst,
                          const int* __restrict__ rp, int* __restrict__ fill,
                          const float* __restrict__ dinv, const float* __restrict__ d2,
                          int* __restrict__ col, float* __restrict__ wl,
                          float* __restrict__ wg) {
    int e = blockIdx.x * blockDim.x + threadIdx.x;
    if (e < E_EDGES) {
        int s = src[e], d = dst[e];
        int pos = rp[d] + atomicAdd(&fill[d], 1);
        col[pos] = s;
        wl[pos]  = dinv[s] * dinv[d];
        wg[pos]  = d2[s] * d2[d];
    }
}

// ---------------- dense GEMM (fp32, 64x64 tile, 4x4 microtile) ----------------
template <int NC, int KD, bool RELU>
__global__ __launch_bounds__(256) void k_gemm(const float* __restrict__ A,
                                              const float* __restrict__ W,
                                              const float* __restrict__ bias,
                                              float* __restrict__ outp) {
    __shared__ float As[16][68];
    __shared__ float Bs[16][68];
    int tid = threadIdx.x;
    int m0 = blockIdx.x * 64, n0 = blockIdx.y * 64;
    int tr = tid >> 4, tc = tid & 15;
    int tr4 = tr * 4, tc4 = tc * 4;
    float acc[4][4] = {};
    int la_row = tid >> 2, la_k = (tid & 3) * 4;
    int lb_k = tid >> 4, lb_n = (tid & 15) * 4;
    for (int k0 = 0; k0 < KD; k0 += 16) {
        __syncthreads();
        float4 fa = *(const float4*)&A[(size_t)(m0 + la_row) * KD + k0 + la_k];
        As[la_k + 0][la_row] = fa.x;
        As[la_k + 1][la_row] = fa.y;
        As[la_k + 2][la_row] = fa.z;
        As[la_k + 3][la_row] = fa.w;
        float4 fb = *(const float4*)&W[(size_t)(k0 + lb_k) * NC + n0 + lb_n];
        *(float4*)&Bs[lb_k][lb_n] = fb;
        __syncthreads();
#pragma unroll
        for (int k = 0; k < 16; ++k) {
            float4 av = *(float4*)&As[k][tr4];
            float4 bv = *(float4*)&Bs[k][tc4];
            rank1(acc[0], av.x, bv);
            rank1(acc[1], av.y, bv);
            rank1(acc[2], av.z, bv);
            rank1(acc[3], av.w, bv);
        }
    }
#pragma unroll
    for (int i = 0; i < 4; ++i) {
        int m = m0 + tr4 + i;
#pragma unroll
        for (int j = 0; j < 4; ++j) {
            int n = n0 + tc4 + j;
            float v = acc[i][j] + bias[n];
            if (RELU) v = v > 0.f ? v : 0.f;
            outp[(size_t)m * NC + n] = v;
        }
    }
}

// ---------------- PE encoder ----------------
__global__ void k_pe0(const float* __restrict__ pos_enc, const float* __restrict__ pw,
                      const float* __restrict__ pb, float* pe, float* raw) {
    int t = threadIdx.x;                       // 0..63
    int r = blockIdx.x * 4 + threadIdx.y;      // row
    float acc = pb[t];
    for (int k = 0; k < 128; ++k)
        acc = fmaf(pos_enc[(size_t)r * 128 + k], pw[k * PEH + t], acc);
    float v = tanhf(acc);
    pe[(size_t)r * PEH + t]  = v;
    raw[(size_t)r * PEH + t] = v;
}

__global__ void k_gamma(const float* __restrict__ pe, const float* __restrict__ gw,
                        const float* __restrict__ gb, const float* __restrict__ temp,
                        float* gamma, int idx) {
    int r = blockIdx.x, t = threadIdx.x;  // block 64
    float g = pe[(size_t)r * PEH + t] * gw[idx * PEH + t];
    for (int m = 32; m; m >>= 1) g += __shfl_xor(g, m);
    if (t == 0) {
        float T = temp[idx];
        T = T > 0.f ? T : 0.f;
        gamma[idx * N_NODES + r] = T / (1.f + expf(-(g + gb[idx])));
    }
}

// ---------------- c = pe @ cor_w + cor_b ----------------
__global__ void k_cmat(const float* __restrict__ pe, const float* __restrict__ cw,
                       const float* __restrict__ cb, float* __restrict__ c) {
    int t = threadIdx.x;
    int r = blockIdx.x * 4 + threadIdx.y;
    float acc = cb[t];
    for (int k = 0; k < PEH; ++k)
        acc = fmaf(pe[(size_t)r * PEH + k], cw[k * PEH + t], acc);
    c[(size_t)r * PEH + t] = acc;
}

// ---------------- fused pe_corr = sigmoid(c c^T) pe  (partials over 4 col-chunks) ---
__global__ __launch_bounds__(256) void k_corr(const float* __restrict__ c,
                                              const float* __restrict__ pe,
                                              float* __restrict__ part) {
    __shared__ float cR[64][68];
    __shared__ float cCT[64][68];  // transposed: cCT[k][col]
    __shared__ float peC[64][68];  // peC[col][d]
    __shared__ float Sm[64][68];
    int tid = threadIdx.x;
    int r0 = blockIdx.x * 64;
    int chunk = blockIdx.y;
    int tr = tid >> 4, tc = tid & 15;
    int tr4 = tr * 4, tc4 = tc * 4;
#pragma unroll
    for (int it = 0; it < 4; ++it) {
        int v = tid + it * 256;
        int row = v >> 4, qf = (v & 15) * 4;
        float4 f = *(const float4*)&c[(size_t)(r0 + row) * PEH + qf];
        *(float4*)&cR[row][qf] = f;
    }
    float acc[4][4] = {};
    for (int tt = 0; tt < 16; ++tt) {
        int c0 = chunk * 1024 + tt * 64;
        __syncthreads();
#pragma unroll
        for (int it = 0; it < 4; ++it) {
            int v = tid + it * 256;
            int row = v >> 4, qf = (v & 15) * 4;
            float4 f = *(const float4*)&c[(size_t)(c0 + row) * PEH + qf];
            cCT[qf + 0][row] = f.x;
            cCT[qf + 1][row] = f.y;
            cCT[qf + 2][row] = f.z;
            cCT[qf + 3][row] = f.w;
            float4 g = *(const float4*)&pe[(size_t)(c0 + row) * PEH + qf];
            *(float4*)&peC[row][qf] = g;
        }
        __syncthreads();
        float s[4][4] = {};
#pragma unroll 4
        for (int k = 0; k < 64; k += 4) {
            float4 A0 = *(float4*)&cR[tr4 + 0][k];
            float4 A1 = *(float4*)&cR[tr4 + 1][k];
            float4 A2 = *(float4*)&cR[tr4 + 2][k];
            float4 A3 = *(float4*)&cR[tr4 + 3][k];
            float4 B0 = *(float4*)&cCT[k + 0][tc4];
            float4 B1 = *(float4*)&cCT[k + 1][tc4];
            float4 B2 = *(float4*)&cCT[k + 2][tc4];
            float4 B3 = *(float4*)&cCT[k + 3][tc4];
            rank1(s[0], A0.x, B0); rank1(s[0], A0.y, B1); rank1(s[0], A0.z, B2); rank1(s[0], A0.w, B3);
            rank1(s[1], A1.x, B0); rank1(s[1], A1.y, B1); rank1(s[1], A1.z, B2); rank1(s[1], A1.w, B3);
            rank1(s[2], A2.x, B0); rank1(s[2], A2.y, B1); rank1(s[2], A2.z, B2); rank1(s[2], A2.w, B3);
            rank1(s[3], A3.x, B0); rank1(s[3], A3.y, B1); rank1(s[3], A3.z, B2); rank1(s[3], A3.w, B3);
        }
#pragma unroll
        for (int i = 0; i < 4; ++i) {
            float4 o;
            o.x = 1.f / (1.f + expf(-s[i][0]));
            o.y = 1.f / (1.f + expf(-s[i][1]));
            o.z = 1.f / (1.f + expf(-s[i][2]));
            o.w = 1.f / (1.f + expf(-s[i][3]));
            *(float4*)&Sm[tr4 + i][tc4] = o;
        }
        __syncthreads();
#pragma unroll 4
        for (int k = 0; k < 64; k += 4) {
            float4 S0 = *(float4*)&Sm[tr4 + 0][k];
            float4 S1 = *(float4*)&Sm[tr4 + 1][k];
            float4 S2 = *(float4*)&Sm[tr4 + 2][k];
            float4 S3 = *(float4*)&Sm[tr4 + 3][k];
            float4 P0 = *(float4*)&peC[k + 0][tc4];
            float4 P1 = *(float4*)&peC[k + 1][tc4];
            float4 P2 = *(float4*)&peC[k + 2][tc4];
            float4 P3 = *(float4*)&peC[k + 3][tc4];
            rank1(acc[0], S0.x, P0); rank1(acc[0], S0.y, P1); rank1(acc[0], S0.z, P2); rank1(acc[0], S0.w, P3);
            rank1(acc[1], S1.x, P0); rank1(acc[1], S1.y, P1); rank1(acc[1], S1.z, P2); rank1(acc[1], S1.w, P3);
            rank1(acc[2], S2.x, P0); rank1(acc[2], S2.y, P1); rank1(acc[2], S2.z, P2); rank1(acc[2], S2.w, P3);
            rank1(acc[3], S3.x, P0); rank1(acc[3], S3.y, P1); rank1(acc[3], S3.z, P2); rank1(acc[3], S3.w, P3);
        }
    }
    float* dst = part + (size_t)chunk * NPE;
#pragma unroll
    for (int i = 0; i < 4; ++i) {
        *(float4*)&dst[(size_t)(r0 + tr4 + i) * PEH + tc4] =
            make_float4(acc[i][0], acc[i][1], acc[i][2], acc[i][3]);
    }
}

// ---------------- ahat (CSR SpMM width 64 + diag) ----------------
__global__ void k_ahat(const float* __restrict__ pe, float* __restrict__ tpo,
                       const int* __restrict__ rp, const int* __restrict__ col,
                       const float* __restrict__ wg, const float* __restrict__ d2) {
    __shared__ int sc[64];
    __shared__ float sw[64];
    int r = blockIdx.x, t = threadIdx.x;  // 64 threads
    int e0 = rp[r], e1 = rp[r + 1];
    float dd = d2[r];
    float acc = dd * dd * pe[(size_t)r * PEH + t];
    for (int ch = e0; ch < e1; ch += 64) {
        int n = min(64, e1 - ch);
        __syncthreads();
        if (t < n) { sc[t] = col[ch + t]; sw[t] = wg[ch + t]; }
        __syncthreads();
        for (int q = 0; q < n; ++q)
            acc = fmaf(sw[q], pe[(size_t)sc[q] * PEH + t], acc);
    }
    tpo[(size_t)r * PEH + t] = acc;
}

// ---------------- pe update + gamma ----------------
__global__ void k_update(const float* __restrict__ tpo, const float* __restrict__ corrp,
                         const float* __restrict__ raw, float* __restrict__ pe,
                         const float* __restrict__ gw, const float* __restrict__ gb,
                         const float* __restrict__ temp, float* __restrict__ gamma,
                         int ip1) {
    int r = blockIdx.x, t = threadIdx.x;  // 64
    int idx = r * PEH + t;
    float corr = corrp[idx] + corrp[NPE + idx] + corrp[2 * NPE + idx] + corrp[3 * NPE + idx];
    float v = 1.5f * tpo[idx] - 0.5f * corr;
    v = 0.1f * raw[idx] + 0.9f * v;
    v = tanhf(v);
    pe[idx] = v;
    float g = v * gw[ip1 * PEH + t];
    for (int m = 32; m; m >>= 1) g += __shfl_xor(g, m);
    if (t == 0) {
        float T = temp[ip1];
        T = T > 0.f ? T : 0.f;
        gamma[ip1 * N_NODES + r] = T / (1.f + expf(-(g + gb[ip1])));
    }
}

// ---------------- SpMM width 128: tmp chain (out = in + A' in) ----------------
__global__ void k_spmm_add(const float* __restrict__ in, float* __restrict__ outp,
                           const int* __restrict__ rp, const int* __restrict__ col,
                           const float* __restrict__ w) {
    __shared__ int sc[128];
    __shared__ float sw[128];
    int r = blockIdx.x, t = threadIdx.x;  // 128
    int e0 = rp[r], e1 = rp[r + 1];
    float acc = in[(size_t)r * OUTD + t];
    for (int ch = e0; ch < e1; ch += 128) {
        int n = min(128, e1 - ch);
        __syncthreads();
        if (t < n) { sc[t] = col[ch + t]; sw[t] = w[ch + t]; }
        __syncthreads();
        for (int q = 0; q < n; ++q)
            acc = fmaf(sw[q], in[(size_t)sc[q] * OUTD + t], acc);
    }
    outp[(size_t)r * OUTD + t] = acc;
}

// ---------------- batched B-step: V_j <- V_j - A' V_j for all j >= s -----------
__global__ void k_bstep(const float* __restrict__ in_base, float* __restrict__ out_base,
                        int s, const int* __restrict__ rp, const int* __restrict__ col,
                        const float* __restrict__ w) {
    __shared__ int sc[128];
    __shared__ float sw[128];
    int j = s + blockIdx.y;
    const float* in = in_base + (size_t)j * NM;
    float* outp = out_base + (size_t)j * NM;
    int r = blockIdx.x, t = threadIdx.x;
    int e0 = rp[r], e1 = rp[r + 1];
    float acc = in[(size_t)r * OUTD + t];
    for (int ch = e0; ch < e1; ch += 128) {
        int n = min(128, e1 - ch);
        __syncthreads();
        if (t < n) { sc[t] = col[ch + t]; sw[t] = w[ch + t]; }
        __syncthreads();
        for (int q = 0; q < n; ++q)
            acc = fmaf(-sw[q], in[(size_t)sc[q] * OUTD + t], acc);
    }
    outp[(size_t)r * OUTD + t] = acc;
}

// ---------------- epilogue ----------------
__global__ void k_out(const float* __restrict__ bufA, const float* __restrict__ bufB,
                      const float* __restrict__ gamma, float* __restrict__ dout) {
    int r = blockIdx.x, t = threadIdx.x;  // 128
    float acc = 0.f;
#pragma unroll
    for (int j = 0; j <= KHOP; ++j) {
        const float* B = (j & 1) ? bufB : bufA;
        acc = fmaf(d_coeff[j] * gamma[j * N_NODES + r],
                   B[(size_t)j * NM + (size_t)r * OUTD + t], acc);
    }
    dout[(size_t)r * OUTD + t] = acc;
}

__global__ void k_pecopy(const float* __restrict__ pe, float* __restrict__ dout) {
    int i = blockIdx.x * blockDim.x + threadIdx.x;
    if (i < NPE) dout[NM + i] = pe[i];
}

// ---------------- host launcher ----------------
extern "C" void kernel_launch(void* const* d_in, const int* in_sizes, int n_in,
                              void* d_out, int out_size, void* d_ws, size_t ws_size,
                              hipStream_t stream) {
    const float* node_feat = (const float*)d_in[0];
    const int*   eidx      = (const int*)d_in[1];
    const float* pos_enc   = (const float*)d_in[2];
    const float* lin1_w    = (const float*)d_in[3];
    const float* lin1_b    = (const float*)d_in[4];
    const float* lin2_w    = (const float*)d_in[5];
    const float* lin2_b    = (const float*)d_in[6];
    const float* pe_w      = (const float*)d_in[7];
    const float* pe_b      = (const float*)d_in[8];
    const float* cor_w     = (const float*)d_in[9];
    const float* cor_b     = (const float*)d_in[10];
    const float* gate_w    = (const float*)d_in[11];
    const float* gate_b    = (const float*)d_in[12];
    const float* temp      = (const float*)d_in[13];
    const int* src = eidx;
    const int* dst = eidx + E_EDGES;
    float* dout = (float*)d_out;

    char* p = (char*)d_ws;
    auto alloc = [&](size_t bytes) -> char* {
        char* r = p;
        p += (bytes + 255) & ~(size_t)255;
        return r;
    };
    int*   outdeg = (int*)alloc(N_NODES * 4);
    int*   indeg  = (int*)alloc(N_NODES * 4);
    int*   fill   = (int*)alloc(N_NODES * 4);
    int*   rp     = (int*)alloc((N_NODES + 1) * 4);
    int*   col    = (int*)alloc(E_EDGES * 4);
    float* wl     = (float*)alloc(E_EDGES * 4);
    float* wg     = (float*)alloc(E_EDGES * 4);
    float* dinv   = (float*)alloc(N_NODES * 4);
    float* d2     = (float*)alloc(N_NODES * 4);
    float* h      = (float*)alloc((size_t)N_NODES * HID * 4);
    float* pe     = (float*)alloc((size_t)NPE * 4);
    float* raw    = (float*)alloc((size_t)NPE * 4);
    float* cmat   = (float*)alloc((size_t)NPE * 4);
    float* tpo    = (float*)alloc((size_t)NPE * 4);
    float* corrp  = (float*)alloc((size_t)4 * NPE * 4);
    float* gamma  = (float*)alloc((size_t)11 * N_NODES * 4);
    float* bufA   = (float*)alloc((size_t)11 * NM * 4);
    float* bufB   = (float*)alloc((size_t)11 * NM * 4);

    hipMemsetAsync(outdeg, 0, N_NODES * 4, stream);
    hipMemsetAsync(indeg, 0, N_NODES * 4, stream);
    hipMemsetAsync(fill, 0, N_NODES * 4, stream);

    k_degrees<<<E_EDGES / 256, 256, 0, stream>>>(src, dst, outdeg, indeg);
    k_invs<<<N_NODES / 256, 256, 0, stream>>>(outdeg, indeg, dinv, d2);
    k_scan<<<1, 64, 0, stream>>>(indeg, rp);
    k_scatter<<<E_EDGES / 256, 256, 0, stream>>>(src, dst, rp, fill, dinv, d2, col, wl, wg);

    // x = relu(nf@W1 + b1)@W2 + b2 ; x0 lives in bufA slot 10 (V_10 = tmp[0])
    k_gemm<HID, IND, true><<<dim3(N_NODES / 64, HID / 64), 256, 0, stream>>>(
        node_feat, lin1_w, lin1_b, h);
    float* x0 = bufA + (size_t)10 * NM;
    k_gemm<OUTD, HID, false><<<dim3(N_NODES / 64, OUTD / 64), 256, 0, stream>>>(
        h, lin2_w, lin2_b, x0);

    k_pe0<<<N_NODES / 4, dim3(64, 4), 0, stream>>>(pos_enc, pe_w, pe_b, pe, raw);
    k_gamma<<<N_NODES, 64, 0, stream>>>(pe, gate_w, gate_b, temp, gamma, 0);

    // tmp chain: slot (10-k) -> slot (9-k);  slot j = tmp[10-j] = V_j initial
    for (int k = 0; k < KHOP; ++k) {
        const float* in = bufA + (size_t)(10 - k) * NM;
        float* outp = bufA + (size_t)(9 - k) * NM;
        k_spmm_add<<<N_NODES, 128, 0, stream>>>(in, outp, rp, col, wl);
    }

    // pe loop (independent of x chains) — collects gamma[1..10]
    for (int i = 0; i < KHOP; ++i) {
        k_cmat<<<N_NODES / 4, dim3(64, 4), 0, stream>>>(pe, cor_w, cor_b, cmat);
        k_corr<<<dim3(64, 4), 256, 0, stream>>>(cmat, pe, corrp);
        k_ahat<<<N_NODES, 64, 0, stream>>>(pe, tpo, rp, col, wg, d2);
        k_update<<<N_NODES, 64, 0, stream>>>(tpo, corrp, raw, pe, gate_w, gate_b,
                                             temp, gamma, i + 1);
    }

    // B-chain: step s applies (I - A') to V_j for all j >= s (ping-pong parity)
    for (int s = 1; s <= KHOP; ++s) {
        const float* inb = (s & 1) ? bufA : bufB;
        float* outb = (s & 1) ? (float*)bufB : bufA;
        k_bstep<<<dim3(N_NODES, 11 - s), 128, 0, stream>>>(inb, outb, s, rp, col, wl);
    }

    k_out<<<N_NODES, 128, 0, stream>>>(bufA, bufB, gamma, dout);
    k_pecopy<<<(NPE + 255) / 256, 256, 0, stream>>>(pe, dout);
}

// Round 2
// 1037.332 us; speedup vs baseline: 1.6346x; 1.6346x over previous
//
#include <hip/hip_runtime.h>
#include <math.h>

constexpr int N_NODES = 4096;
constexpr int E_EDGES = 131072;
constexpr int IND     = 1024;
constexpr int HID     = 512;
constexpr int OUTD    = 128;
constexpr int PEH     = 64;
constexpr int KHOP    = 10;
constexpr int NPE     = N_NODES * PEH;    // 262144
constexpr int NM      = N_NODES * OUTD;   // 524288
constexpr int NCHUNK  = 8;                // corr column chunks

__constant__ float d_coeff[11] = {
    1.f/1024.f, 10.f/1024.f, 45.f/1024.f, 120.f/1024.f, 210.f/1024.f,
    252.f/1024.f, 210.f/1024.f, 120.f/1024.f, 45.f/1024.f, 10.f/1024.f, 1.f/1024.f};

typedef __attribute__((ext_vector_type(8))) short bf16x8;
typedef __attribute__((ext_vector_type(4))) float f32x4;

__device__ __forceinline__ void rank1(float (&s)[4], float a, const float4 b) {
    s[0] = fmaf(a, b.x, s[0]);
    s[1] = fmaf(a, b.y, s[1]);
    s[2] = fmaf(a, b.z, s[2]);
    s[3] = fmaf(a, b.w, s[3]);
}

// ---------------- graph prep ----------------
__global__ void k_degrees(const int* __restrict__ src, const int* __restrict__ dst,
                          int* outdeg, int* indeg) {
    int e = blockIdx.x * blockDim.x + threadIdx.x;
    if (e < E_EDGES) {
        atomicAdd(&outdeg[src[e]], 1);
        atomicAdd(&indeg[dst[e]], 1);
    }
}

__global__ void k_invs(const int* __restrict__ outdeg, const int* __restrict__ indeg,
                       float* dinv, float* d2) {
    int i = blockIdx.x * blockDim.x + threadIdx.x;
    if (i < N_NODES) {
        int od = outdeg[i];
        dinv[i] = od > 0 ? 1.0f / sqrtf((float)od) : 0.0f;
        d2[i]   = 1.0f / sqrtf((float)indeg[i] + 1.0f);
    }
}

__global__ void k_scan(const int* __restrict__ cnt, int* __restrict__ rp) {
    int lane = threadIdx.x;  // 0..63
    int base = lane * 64;
    int sum = 0;
    for (int j = 0; j < 64; ++j) sum += cnt[base + j];
    int incl = sum;
    for (int off = 1; off < 64; off <<= 1) {
        int nv = __shfl_up(incl, off);
        if (lane >= off) incl += nv;
    }
    int run = incl - sum;
    for (int j = 0; j < 64; ++j) { rp[base + j] = run; run += cnt[base + j]; }
    if (lane == 63) rp[N_NODES] = run;
}

__global__ void k_scatter(const int* __restrict__ src, const int* __restrict__ dst,
                          const int* __restrict__ rp, int* __restrict__ fill,
                          const float* __restrict__ dinv, const float* __restrict__ d2,
                          int* __restrict__ col, float* __restrict__ wl,
                          float* __restrict__ wg) {
    int e = blockIdx.x * blockDim.x + threadIdx.x;
    if (e < E_EDGES) {
        int s = src[e], d = dst[e];
        int pos = rp[d] + atomicAdd(&fill[d], 1);
        col[pos] = s;
        wl[pos]  = dinv[s] * dinv[d];
        wg[pos]  = d2[s] * d2[d];
    }
}

// ---------------- dense GEMM (fp32, 64x64 tile, 4x4 microtile) ----------------
template <int NC, int KD, bool RELU>
__global__ __launch_bounds__(256) void k_gemm(const float* __restrict__ A,
                                              const float* __restrict__ W,
                                              const float* __restrict__ bias,
                                              float* __restrict__ outp) {
    __shared__ float As[16][68];
    __shared__ float Bs[16][68];
    int tid = threadIdx.x;
    int m0 = blockIdx.x * 64, n0 = blockIdx.y * 64;
    int tr = tid >> 4, tc = tid & 15;
    int tr4 = tr * 4, tc4 = tc * 4;
    float acc[4][4] = {};
    int la_row = tid >> 2, la_k = (tid & 3) * 4;
    int lb_k = tid >> 4, lb_n = (tid & 15) * 4;
    for (int k0 = 0; k0 < KD; k0 += 16) {
        __syncthreads();
        float4 fa = *(const float4*)&A[(size_t)(m0 + la_row) * KD + k0 + la_k];
        As[la_k + 0][la_row] = fa.x;
        As[la_k + 1][la_row] = fa.y;
        As[la_k + 2][la_row] = fa.z;
        As[la_k + 3][la_row] = fa.w;
        float4 fb = *(const float4*)&W[(size_t)(k0 + lb_k) * NC + n0 + lb_n];
        *(float4*)&Bs[lb_k][lb_n] = fb;
        __syncthreads();
#pragma unroll
        for (int k = 0; k < 16; ++k) {
            float4 av = *(float4*)&As[k][tr4];
            float4 bv = *(float4*)&Bs[k][tc4];
            rank1(acc[0], av.x, bv);
            rank1(acc[1], av.y, bv);
            rank1(acc[2], av.z, bv);
            rank1(acc[3], av.w, bv);
        }
    }
#pragma unroll
    for (int i = 0; i < 4; ++i) {
        int m = m0 + tr4 + i;
#pragma unroll
        for (int j = 0; j < 4; ++j) {
            int n = n0 + tc4 + j;
            float v = acc[i][j] + bias[n];
            if (RELU) v = v > 0.f ? v : 0.f;
            outp[(size_t)m * NC + n] = v;
        }
    }
}

// ---------------- PE encoder ----------------
__global__ void k_pe0(const float* __restrict__ pos_enc, const float* __restrict__ pw,
                      const float* __restrict__ pb, float* pe, float* raw) {
    int t = threadIdx.x;
    int r = blockIdx.x * 4 + threadIdx.y;
    float acc = pb[t];
    for (int k = 0; k < 128; ++k)
        acc = fmaf(pos_enc[(size_t)r * 128 + k], pw[k * PEH + t], acc);
    float v = tanhf(acc);
    pe[(size_t)r * PEH + t]  = v;
    raw[(size_t)r * PEH + t] = v;
}

__global__ void k_gamma(const float* __restrict__ pe, const float* __restrict__ gw,
                        const float* __restrict__ gb, const float* __restrict__ temp,
                        float* gamma, int idx) {
    int r = blockIdx.x, t = threadIdx.x;
    float g = pe[(size_t)r * PEH + t] * gw[idx * PEH + t];
    for (int m = 32; m; m >>= 1) g += __shfl_xor(g, m);
    if (t == 0) {
        float T = temp[idx];
        T = T > 0.f ? T : 0.f;
        gamma[idx * N_NODES + r] = T / (1.f + expf(-(g + gb[idx])));
    }
}

// ---------------- c = pe @ cor_w + cor_b ----------------
__global__ void k_cmat(const float* __restrict__ pe, const float* __restrict__ cw,
                       const float* __restrict__ cb, float* __restrict__ c) {
    int t = threadIdx.x;
    int r = blockIdx.x * 4 + threadIdx.y;
    float acc = cb[t];
    for (int k = 0; k < PEH; ++k)
        acc = fmaf(pe[(size_t)r * PEH + k], cw[k * PEH + t], acc);
    c[(size_t)r * PEH + t] = acc;
}

// ================= MFMA corr: pe_corr = sigmoid(c c^T) @ pe =================
// hi/lo bf16 split (3 MFMA passes per GEMM) keeps ~2^-16 relative accuracy.
__device__ __forceinline__ int swz(int row, int col) {
    // element index into a 64x64 ushort LDS tile, XOR-swizzled at 16B granularity
    return row * 64 + (col ^ ((row & 7) << 3));
}

__device__ __forceinline__ void split_bf16(float x, short& h, short& l) {
    unsigned bx = __float_as_uint(x);
    h = (short)(bx >> 16);
    float hf = __uint_as_float(bx & 0xffff0000u);
    l = (short)(__float_as_uint(x - hf) >> 16);
}

// stage 64 rows x 64 cols of f32 matrix g (rows n0..n0+63) as hi/lo bf16, row-major
__device__ __forceinline__ void stage_rm(const float* __restrict__ g, int n0,
                                         ushort* th, ushort* tl, int tid) {
    int row = tid >> 2, cb = (tid & 3) * 16;
    const float* s = &g[(size_t)(n0 + row) * 64 + cb];
    float4 f0 = *(const float4*)&s[0];
    float4 f1 = *(const float4*)&s[4];
    float4 f2 = *(const float4*)&s[8];
    float4 f3 = *(const float4*)&s[12];
    float v[16] = {f0.x, f0.y, f0.z, f0.w, f1.x, f1.y, f1.z, f1.w,
                   f2.x, f2.y, f2.z, f2.w, f3.x, f3.y, f3.z, f3.w};
    bf16x8 h0, l0, h1, l1;
#pragma unroll
    for (int j = 0; j < 8; ++j) {
        short h, l;
        split_bf16(v[j], h, l);
        h0[j] = h; l0[j] = l;
        split_bf16(v[8 + j], h, l);
        h1[j] = h; l1[j] = l;
    }
    *(bf16x8*)&th[swz(row, cb)]     = h0;
    *(bf16x8*)&th[swz(row, cb + 8)] = h1;
    *(bf16x8*)&tl[swz(row, cb)]     = l0;
    *(bf16x8*)&tl[swz(row, cb + 8)] = l1;
}

// stage 64x64 tile of g (rows n0..n0+63) TRANSPOSED: t[d][node] (hi/lo bf16)
__device__ __forceinline__ void stage_tr(const float* __restrict__ g, int n0,
                                         ushort* th, ushort* tl, int tid) {
    int row = tid >> 2, cb = (tid & 3) * 16;
    const float* s = &g[(size_t)(n0 + row) * 64 + cb];
    float4 f0 = *(const float4*)&s[0];
    float4 f1 = *(const float4*)&s[4];
    float4 f2 = *(const float4*)&s[8];
    float4 f3 = *(const float4*)&s[12];
    float v[16] = {f0.x, f0.y, f0.z, f0.w, f1.x, f1.y, f1.z, f1.w,
                   f2.x, f2.y, f2.z, f2.w, f3.x, f3.y, f3.z, f3.w};
#pragma unroll
    for (int j = 0; j < 16; ++j) {
        int d = cb + j;
        short h, l;
        split_bf16(v[j], h, l);
        th[swz(d, row)] = (ushort)h;
        tl[swz(d, row)] = (ushort)l;
    }
}

// one bf16 MFMA pass over a 16(row strip) x 64 x K=64 block: acc[n] over 4 col tiles
__device__ __forceinline__ void mm_pass(const ushort* __restrict__ A,
                                        const ushort* __restrict__ B,
                                        int wrow, int lm, int lq, f32x4 (&acc)[4]) {
#pragma unroll
    for (int kt = 0; kt < 2; ++kt) {
        int kb = kt * 32 + lq * 8;
        bf16x8 a = *(const bf16x8*)&A[swz(wrow + lm, kb)];
#pragma unroll
        for (int n = 0; n < 4; ++n) {
            bf16x8 b = *(const bf16x8*)&B[swz(n * 16 + lm, kb)];
            acc[n] = __builtin_amdgcn_mfma_f32_16x16x32_bf16(a, b, acc[n], 0, 0, 0);
        }
    }
}

__global__ __launch_bounds__(256) void k_corr_mfma(const float* __restrict__ c,
                                                   const float* __restrict__ pe,
                                                   float* __restrict__ part) {
    __shared__ __align__(16) ushort cRh[4096];
    __shared__ __align__(16) ushort cRl[4096];
    __shared__ __align__(16) ushort cCh[4096];
    __shared__ __align__(16) ushort cCl[4096];
    __shared__ __align__(16) ushort pTh[4096];
    __shared__ __align__(16) ushort pTl[4096];
    __shared__ __align__(16) ushort Sh[4096];
    __shared__ __align__(16) ushort Sl[4096];

    int tid = threadIdx.x;
    int r0 = blockIdx.x * 64;
    int chunk = blockIdx.y;  // 0..NCHUNK-1
    int w = tid >> 6;        // wave 0..3, owns rows [16w,16w+16)
    int l = tid & 63;
    int lm = l & 15, lq = l >> 4;
    int wrow = w * 16;

    stage_rm(c, r0, cRh, cRl, tid);

    f32x4 pacc[4];
#pragma unroll
    for (int n = 0; n < 4; ++n) pacc[n] = (f32x4){0.f, 0.f, 0.f, 0.f};

    for (int t = 0; t < 512 / 64; ++t) {
        int c0 = chunk * 512 + t * 64;
        __syncthreads();  // previous iter's reads of cC/pT/S done
        stage_rm(c, c0, cCh, cCl, tid);
        stage_tr(pe, c0, pTh, pTl, tid);
        __syncthreads();

        // GEMM1: S = cR @ cC^T  (hi*hi + hi*lo + lo*hi)
        f32x4 sacc[4];
#pragma unroll
        for (int n = 0; n < 4; ++n) sacc[n] = (f32x4){0.f, 0.f, 0.f, 0.f};
        mm_pass(cRh, cCh, wrow, lm, lq, sacc);
        mm_pass(cRh, cCl, wrow, lm, lq, sacc);
        mm_pass(cRl, cCh, wrow, lm, lq, sacc);

        // sigmoid, split, store to LDS
#pragma unroll
        for (int n = 0; n < 4; ++n) {
#pragma unroll
            for (int r = 0; r < 4; ++r) {
                float x = sacc[n][r];
                float sg = 1.0f / (1.0f + __expf(-x));
                int row = wrow + lq * 4 + r;
                int colj = n * 16 + lm;
                short h, lo2;
                split_bf16(sg, h, lo2);
                Sh[swz(row, colj)] = (ushort)h;
                Sl[swz(row, colj)] = (ushort)lo2;
            }
        }
        __syncthreads();

        // GEMM2: P += sig(S) @ pe   (B^T staged as pT[d][col])
        mm_pass(Sh, pTh, wrow, lm, lq, pacc);
        mm_pass(Sh, pTl, wrow, lm, lq, pacc);
        mm_pass(Sl, pTh, wrow, lm, lq, pacc);
    }

    float* dst = part + (size_t)chunk * NPE;
#pragma unroll
    for (int n = 0; n < 4; ++n) {
#pragma unroll
        for (int r = 0; r < 4; ++r) {
            int row = r0 + wrow + lq * 4 + r;
            int d = n * 16 + lm;
            dst[(size_t)row * PEH + d] = pacc[n][r];
        }
    }
}

// ---------------- ahat (CSR SpMM width 64 + diag) ----------------
__global__ void k_ahat(const float* __restrict__ pe, float* __restrict__ tpo,
                       const int* __restrict__ rp, const int* __restrict__ col,
                       const float* __restrict__ wg, const float* __restrict__ d2) {
    __shared__ int sc[64];
    __shared__ float sw[64];
    int r = blockIdx.x, t = threadIdx.x;
    int e0 = rp[r], e1 = rp[r + 1];
    float dd = d2[r];
    float acc = dd * dd * pe[(size_t)r * PEH + t];
    for (int ch = e0; ch < e1; ch += 64) {
        int n = min(64, e1 - ch);
        __syncthreads();
        if (t < n) { sc[t] = col[ch + t]; sw[t] = wg[ch + t]; }
        __syncthreads();
        for (int q = 0; q < n; ++q)
            acc = fmaf(sw[q], pe[(size_t)sc[q] * PEH + t], acc);
    }
    tpo[(size_t)r * PEH + t] = acc;
}

// ---------------- pe update + gamma ----------------
__global__ void k_update(const float* __restrict__ tpo, const float* __restrict__ corrp,
                         const float* __restrict__ raw, float* __restrict__ pe,
                         const float* __restrict__ gw, const float* __restrict__ gb,
                         const float* __restrict__ temp, float* __restrict__ gamma,
                         int ip1) {
    int r = blockIdx.x, t = threadIdx.x;
    int idx = r * PEH + t;
    float corr = 0.f;
#pragma unroll
    for (int p = 0; p < NCHUNK; ++p) corr += corrp[(size_t)p * NPE + idx];
    float v = 1.5f * tpo[idx] - 0.5f * corr;
    v = 0.1f * raw[idx] + 0.9f * v;
    v = tanhf(v);
    pe[idx] = v;
    float g = v * gw[ip1 * PEH + t];
    for (int m = 32; m; m >>= 1) g += __shfl_xor(g, m);
    if (t == 0) {
        float T = temp[ip1];
        T = T > 0.f ? T : 0.f;
        gamma[ip1 * N_NODES + r] = T / (1.f + expf(-(g + gb[ip1])));
    }
}

// ---------------- SpMM width 128: tmp chain (out = in + A' in) ----------------
__global__ void k_spmm_add(const float* __restrict__ in, float* __restrict__ outp,
                           const int* __restrict__ rp, const int* __restrict__ col,
                           const float* __restrict__ w) {
    __shared__ int sc[128];
    __shared__ float sw[128];
    int r = blockIdx.x, t = threadIdx.x;
    int e0 = rp[r], e1 = rp[r + 1];
    float acc = in[(size_t)r * OUTD + t];
    for (int ch = e0; ch < e1; ch += 128) {
        int n = min(128, e1 - ch);
        __syncthreads();
        if (t < n) { sc[t] = col[ch + t]; sw[t] = w[ch + t]; }
        __syncthreads();
        for (int q = 0; q < n; ++q)
            acc = fmaf(sw[q], in[(size_t)sc[q] * OUTD + t], acc);
    }
    outp[(size_t)r * OUTD + t] = acc;
}

// ---------------- batched B-step: V_j <- V_j - A' V_j for all j >= s -----------
__global__ void k_bstep(const float* __restrict__ in_base, float* __restrict__ out_base,
                        int s, const int* __restrict__ rp, const int* __restrict__ col,
                        const float* __restrict__ w) {
    __shared__ int sc[128];
    __shared__ float sw[128];
    int j = s + blockIdx.y;
    const float* in = in_base + (size_t)j * NM;
    float* outp = out_base + (size_t)j * NM;
    int r = blockIdx.x, t = threadIdx.x;
    int e0 = rp[r], e1 = rp[r + 1];
    float acc = in[(size_t)r * OUTD + t];
    for (int ch = e0; ch < e1; ch += 128) {
        int n = min(128, e1 - ch);
        __syncthreads();
        if (t < n) { sc[t] = col[ch + t]; sw[t] = w[ch + t]; }
        __syncthreads();
        for (int q = 0; q < n; ++q)
            acc = fmaf(-sw[q], in[(size_t)sc[q] * OUTD + t], acc);
    }
    outp[(size_t)r * OUTD + t] = acc;
}

// ---------------- epilogue ----------------
__global__ void k_out(const float* __restrict__ bufA, const float* __restrict__ bufB,
                      const float* __restrict__ gamma, float* __restrict__ dout) {
    int r = blockIdx.x, t = threadIdx.x;
    float acc = 0.f;
#pragma unroll
    for (int j = 0; j <= KHOP; ++j) {
        const float* B = (j & 1) ? bufB : bufA;
        acc = fmaf(d_coeff[j] * gamma[j * N_NODES + r],
                   B[(size_t)j * NM + (size_t)r * OUTD + t], acc);
    }
    dout[(size_t)r * OUTD + t] = acc;
}

__global__ void k_pecopy(const float* __restrict__ pe, float* __restrict__ dout) {
    int i = blockIdx.x * blockDim.x + threadIdx.x;
    if (i < NPE) dout[NM + i] = pe[i];
}

// ---------------- host launcher ----------------
extern "C" void kernel_launch(void* const* d_in, const int* in_sizes, int n_in,
                              void* d_out, int out_size, void* d_ws, size_t ws_size,
                              hipStream_t stream) {
    const float* node_feat = (const float*)d_in[0];
    const int*   eidx      = (const int*)d_in[1];
    const float* pos_enc   = (const float*)d_in[2];
    const float* lin1_w    = (const float*)d_in[3];
    const float* lin1_b    = (const float*)d_in[4];
    const float* lin2_w    = (const float*)d_in[5];
    const float* lin2_b    = (const float*)d_in[6];
    const float* pe_w      = (const float*)d_in[7];
    const float* pe_b      = (const float*)d_in[8];
    const float* cor_w     = (const float*)d_in[9];
    const float* cor_b     = (const float*)d_in[10];
    const float* gate_w    = (const float*)d_in[11];
    const float* gate_b    = (const float*)d_in[12];
    const float* temp      = (const float*)d_in[13];
    const int* src = eidx;
    const int* dst = eidx + E_EDGES;
    float* dout = (float*)d_out;

    char* p = (char*)d_ws;
    auto alloc = [&](size_t bytes) -> char* {
        char* r = p;
        p += (bytes + 255) & ~(size_t)255;
        return r;
    };
    int*   outdeg = (int*)alloc(N_NODES * 4);
    int*   indeg  = (int*)alloc(N_NODES * 4);
    int*   fill   = (int*)alloc(N_NODES * 4);
    int*   rp     = (int*)alloc((N_NODES + 1) * 4);
    int*   col    = (int*)alloc(E_EDGES * 4);
    float* wl     = (float*)alloc(E_EDGES * 4);
    float* wg     = (float*)alloc(E_EDGES * 4);
    float* dinv   = (float*)alloc(N_NODES * 4);
    float* d2     = (float*)alloc(N_NODES * 4);
    float* h      = (float*)alloc((size_t)N_NODES * HID * 4);
    float* pe     = (float*)alloc((size_t)NPE * 4);
    float* raw    = (float*)alloc((size_t)NPE * 4);
    float* cmat   = (float*)alloc((size_t)NPE * 4);
    float* tpo    = (float*)alloc((size_t)NPE * 4);
    float* corrp  = (float*)alloc((size_t)NCHUNK * NPE * 4);
    float* gamma  = (float*)alloc((size_t)11 * N_NODES * 4);
    float* bufA   = (float*)alloc((size_t)11 * NM * 4);
    float* bufB   = (float*)alloc((size_t)11 * NM * 4);

    hipMemsetAsync(outdeg, 0, N_NODES * 4, stream);
    hipMemsetAsync(indeg, 0, N_NODES * 4, stream);
    hipMemsetAsync(fill, 0, N_NODES * 4, stream);

    k_degrees<<<E_EDGES / 256, 256, 0, stream>>>(src, dst, outdeg, indeg);
    k_invs<<<N_NODES / 256, 256, 0, stream>>>(outdeg, indeg, dinv, d2);
    k_scan<<<1, 64, 0, stream>>>(indeg, rp);
    k_scatter<<<E_EDGES / 256, 256, 0, stream>>>(src, dst, rp, fill, dinv, d2, col, wl, wg);

    k_gemm<HID, IND, true><<<dim3(N_NODES / 64, HID / 64), 256, 0, stream>>>(
        node_feat, lin1_w, lin1_b, h);
    float* x0 = bufA + (size_t)10 * NM;
    k_gemm<OUTD, HID, false><<<dim3(N_NODES / 64, OUTD / 64), 256, 0, stream>>>(
        h, lin2_w, lin2_b, x0);

    k_pe0<<<N_NODES / 4, dim3(64, 4), 0, stream>>>(pos_enc, pe_w, pe_b, pe, raw);
    k_gamma<<<N_NODES, 64, 0, stream>>>(pe, gate_w, gate_b, temp, gamma, 0);

    for (int k = 0; k < KHOP; ++k) {
        const float* in = bufA + (size_t)(10 - k) * NM;
        float* outp = bufA + (size_t)(9 - k) * NM;
        k_spmm_add<<<N_NODES, 128, 0, stream>>>(in, outp, rp, col, wl);
    }

    for (int i = 0; i < KHOP; ++i) {
        k_cmat<<<N_NODES / 4, dim3(64, 4), 0, stream>>>(pe, cor_w, cor_b, cmat);
        k_corr_mfma<<<dim3(N_NODES / 64, NCHUNK), 256, 0, stream>>>(cmat, pe, corrp);
        k_ahat<<<N_NODES, 64, 0, stream>>>(pe, tpo, rp, col, wg, d2);
        k_update<<<N_NODES, 64, 0, stream>>>(tpo, corrp, raw, pe, gate_w, gate_b,
                                             temp, gamma, i + 1);
    }

    for (int s = 1; s <= KHOP; ++s) {
        const float* inb = (s & 1) ? bufA : bufB;
        float* outb = (s & 1) ? (float*)bufB : bufA;
        k_bstep<<<dim3(N_NODES, 11 - s), 128, 0, stream>>>(inb, outb, s, rp, col, wl);
    }

    k_out<<<N_NODES, 128, 0, stream>>>(bufA, bufB, gamma, dout);
    k_pecopy<<<(NPE + 255) / 256, 256, 0, stream>>>(pe, dout);
}